// Round 9
// baseline (139.836 us; speedup 1.0000x reference)
//
#include <hip/hip_runtime.h>
#include <hip/hip_bf16.h>

typedef float    f32x16 __attribute__((ext_vector_type(16)));
typedef _Float16 f16x8  __attribute__((ext_vector_type(8)));
typedef _Float16 f16x4  __attribute__((ext_vector_type(4)));
typedef _Float16 f16x2  __attribute__((ext_vector_type(2)));

// votes (fp16, full batch): [b(32)][h(30)][i(8)][w(30)][oa(256)]
// = 32*30*8*7680*2 B = 117,964,800 B ; W_t fp16 [256][144] after it.
#define VSLAB  7680
#define WT_OFF 117964800

// ---------------------------------------------------------------------------
// Kernel 0: W [144][256] f32 -> W_t [co(256)][tap(9)][kd(16)] fp16
// (k' = tap*16 + kd reordering; A side uses the same order)
// ---------------------------------------------------------------------------
__global__ __launch_bounds__(256) void prep_wt_kernel(
    const float* __restrict__ W, _Float16* __restrict__ wt)
{
    const int k = blockIdx.x;      // 0..143 ; kd = k/9, tap = k%9
    const int t = threadIdx.x;     // co
    wt[t * 144 + (k % 9) * 16 + (k / 9)] = (_Float16)W[k * 256 + t];
}

// ---------------------------------------------------------------------------
// Kernel 1: conv -> votes via MFMA fp16 (fp32 accum).
// Block (b,d,h-pair), 512 threads / 8 waves: D[hw=64][co=256], K=144.
// xs staged kd-innermost -> A-frags are direct vector LDS reads (no im2col).
// Epilogue transposes through LDS ob for coalesced f16x8 global stores.
// ---------------------------------------------------------------------------
__global__ __launch_bounds__(512, 4) void conv_mfma_kernel(
    const float* __restrict__ x, const _Float16* __restrict__ wt,
    _Float16* __restrict__ votes)
{
    const int b  = blockIdx.x;     // 32
    const int d  = blockIdx.y;     // 8
    const int h0 = blockIdx.z * 2; // 0,2,..,28
    const int t  = threadIdx.x;    // 0..511

    __shared__ union {
        _Float16 xs[4][36][20];    // [row][col][kd pad20] = 5760 B
        _Float16 ob[64][256];      // [hw][co] = 32 KB
    } u;

    // --- stage x: 2304 elems -> xs[r][z][kd] fp16 (cols 32..35 zero)
    {
        const float* xb = x + (size_t)b * (128 * 1024) + (size_t)d * (16 * 1024);
        #pragma unroll
        for (int j = 0; j < 5; ++j) {
            int idx = t + j * 512;
            if (idx < 2304) {
                int kd  = idx / 144;
                int rem = idx - kd * 144;
                int r   = rem / 36;
                int z   = rem - r * 36;
                float v = (z < 32) ? xb[kd * 1024 + (h0 + r) * 32 + z] : 0.f;
                u.xs[r][z][kd] = (_Float16)v;
            }
        }
    }
    __syncthreads();

    const int lane = t & 63;
    const int wv   = t >> 6;        // 0..7
    const int l31  = lane & 31;
    const int kb   = lane >> 5;     // 0/1
    const int hwt  = wv >> 2;       // h-row 0/1
    const int ct0  = (wv & 3) * 2;  // first of 2 co-tiles

    // --- A-frags: af[s][j] = X[hw][k'=s*16+kb*8+j] = xs[hwt+kh][l31+kw][kb*8+j]
    f16x8 af[9];
    #pragma unroll
    for (int s = 0; s < 9; ++s) {
        const int kh = s / 3, kw = s - 3 * kh;
        const _Float16* ap = &u.xs[hwt + kh][l31 + kw][kb * 8];
        f16x4 lo = *(const f16x4*)(ap);
        f16x4 hi = *(const f16x4*)(ap + 4);
        af[s] = __builtin_shufflevector(lo, hi, 0, 1, 2, 3, 4, 5, 6, 7);
    }
    __syncthreads();   // all waves done reading xs; ob reuse is now safe

    f32x16 acc[2];
    #pragma unroll
    for (int c = 0; c < 2; ++c)
        #pragma unroll
        for (int e = 0; e < 16; ++e) acc[c][e] = 0.f;

    // --- MFMA: 2 co-tiles x 9 K-steps; B frags straight from L2-hot W_t
    #pragma unroll
    for (int cc = 0; cc < 2; ++cc) {
        const int co = (ct0 + cc) * 32 + l31;
        const _Float16* wp = wt + (size_t)co * 144 + kb * 8;
        #pragma unroll
        for (int s = 0; s < 9; ++s) {
            f16x8 bf = *(const f16x8*)(wp + s * 16);
            acc[cc] = __builtin_amdgcn_mfma_f32_32x32x16_f16(af[s], bf, acc[cc], 0, 0, 0);
        }
    }

    // --- acc -> ob (b16 writes, lane-consecutive co: conflict-free)
    #pragma unroll
    for (int cc = 0; cc < 2; ++cc) {
        const int co = (ct0 + cc) * 32 + l31;
        #pragma unroll
        for (int r = 0; r < 16; ++r) {
            const int wrow = (r & 3) + 8 * (r >> 2) + 4 * kb;
            u.ob[hwt * 32 + wrow][co] = (_Float16)acc[cc][r];
        }
    }
    __syncthreads();

    // --- coalesced copy out: 2048 f16x8 granules
    #pragma unroll
    for (int j = 0; j < 4; ++j) {
        int g   = t + j * 512;        // 0..2047
        int row = g >> 5;             // 0..63 = hp*32 + w
        int c8  = (g & 31) * 8;
        int w   = row & 31;
        if (w < 30) {
            _Float16* vb = votes + (size_t)(((b * 30 + h0 + (row >> 5)) * 8) + d) * VSLAB
                         + w * 256 + c8;
            *(f16x8*)vb = *(const f16x8*)&u.ob[row][c8];
        }
    }
}

// ---------------------------------------------------------------------------
// Kernel 2: routing, fully LDS-resident votes. Block per (b,h), 256 threads.
// (unchanged from round 8)
// ---------------------------------------------------------------------------
__global__ __launch_bounds__(256) void routing_kernel(
    const _Float16* __restrict__ votes, const float* __restrict__ bias,
    float* __restrict__ out)
{
    const int h = blockIdx.x;    // 30
    const int b = blockIdx.y;    // 32
    const int t = threadIdx.x;
    const int o = t >> 4;        // phase-B thread's output capsule

    __shared__ _Float16 vlds  [8 * 30 * 258];   // 123,840 B
    __shared__ float    logits[8 * 16 * 31];    //  15,872 B
    __shared__ _Float16 route16[8 * 16 * 30];   //   7,680 B
    __shared__ _Float16 act16 [30 * 258];       //  15,480 B

    // ---- stage votes slab: 7680 granules of 16B, coalesced
    {
        const _Float16* vg = votes + (size_t)(b * 30 + h) * (8 * VSLAB);
        #pragma unroll
        for (int j = 0; j < 30; ++j) {
            int g = t + j * 256;          // 0..7679
            int i = g / 960;
            int r = g - i * 960;
            int w = r >> 5;
            int c = r & 31;
            f16x8 v = *(const f16x8*)(vg + (size_t)g * 8);
            *(f16x8*)&vlds[(i * 30 + w) * 258 + c * 8] = v;
        }
    }
    for (int j = t; j < 8 * 16 * 31; j += 256) logits[j] = 0.f;
    __syncthreads();

    const float bias_t = bias[t];
    const int iA = t / 30;               // phase A/C mapping (t<240)
    const int wA = t - iA * 30;

    float pre[30];
    float scale = 0.f;

    for (int it = 0; it < 3; ++it) {
        // ---- Phase A: route = softmax_o(logits); threads (i,w)
        if (t < 240) {
            float l[16], m = -1e30f;
            #pragma unroll
            for (int oo = 0; oo < 16; ++oo) {
                l[oo] = logits[(iA * 16 + oo) * 31 + wA];
                m = fmaxf(m, l[oo]);
            }
            float s = 0.f;
            #pragma unroll
            for (int oo = 0; oo < 16; ++oo) { l[oo] = __expf(l[oo] - m); s += l[oo]; }
            float inv = 1.f / s;
            #pragma unroll
            for (int oo = 0; oo < 16; ++oo)
                route16[(iA * 16 + oo) * 30 + wA] = (_Float16)(l[oo] * inv);
        }
        __syncthreads();

        // ---- Phase B: thread (o,a)=t: pre[w] = bias + sum_i route*votes
        #pragma unroll
        for (int w = 0; w < 30; ++w) pre[w] = bias_t;
        #pragma unroll
        for (int i = 0; i < 8; ++i) {
            const _Float16* vrow = &vlds[i * 30 * 258 + t];
            const _Float16* rrow = &route16[(i * 16 + o) * 30];
            #pragma unroll
            for (int w = 0; w < 30; ++w)
                pre[w] = fmaf((float)rrow[w], (float)vrow[w * 258], pre[w]);
        }
        float s2 = 0.f;
        #pragma unroll
        for (int w = 0; w < 30; ++w) s2 = fmaf(pre[w], pre[w], s2);
        scale = s2 / ((1.f + s2) * sqrtf(s2 + 1e-7f));

        if (it < 2) {
            #pragma unroll
            for (int w = 0; w < 30; ++w)
                act16[w * 258 + t] = (_Float16)(scale * pre[w]);
            __syncthreads();
            // ---- Phase C: thread (i,w): logits[i,o,w] += sum_a v*act
            if (t < 240) {
                const _Float16* vrow = &vlds[(iA * 30 + wA) * 258];
                const _Float16* arow = &act16[wA * 258];
                #pragma unroll
                for (int oo = 0; oo < 16; ++oo) {
                    float s = 0.f;
                    #pragma unroll
                    for (int k = 0; k < 8; ++k) {
                        f16x2 v2 = *(const f16x2*)&vrow[oo * 16 + 2 * k];
                        f16x2 a2 = *(const f16x2*)&arow[oo * 16 + 2 * k];
                        s = fmaf((float)v2[0], (float)a2[0], s);
                        s = fmaf((float)v2[1], (float)a2[1], s);
                    }
                    logits[(iA * 16 + oo) * 31 + wA] += s;
                }
            }
            __syncthreads();
        }
    }

    // ---- output: out[b,h,w,o,a] from registers, coalesced
    float* ob = out + (size_t)((b * 30 + h) * 30) * 256;
    #pragma unroll
    for (int w = 0; w < 30; ++w) ob[w * 256 + t] = scale * pre[w];
}

extern "C" void kernel_launch(void* const* d_in, const int* in_sizes, int n_in,
                              void* d_out, int out_size, void* d_ws, size_t ws_size,
                              hipStream_t stream)
{
    const float* x    = (const float*)d_in[0];  // [32,32,32,8,16]
    const float* Wt   = (const float*)d_in[1];  // [16,3,3,1,256] = [144][256]
    const float* bias = (const float*)d_in[2];  // [16,16,1,1]
    float* out = (float*)d_out;                 // [32,30,30,16,16]
    _Float16* votes = (_Float16*)d_ws;                     // 117,964,800 B
    _Float16* wt_h  = (_Float16*)((char*)d_ws + WT_OFF);   // [256][144] fp16

    prep_wt_kernel<<<dim3(144), 256, 0, stream>>>(Wt, wt_h);
    conv_mfma_kernel<<<dim3(32, 8, 15), 512, 0, stream>>>(x, wt_h, votes);
    routing_kernel<<<dim3(30, 32), 256, 0, stream>>>(votes, bias, out);
}

// Round 10
// 115.058 us; speedup vs baseline: 1.2154x; 1.2154x over previous
//
#include <hip/hip_runtime.h>
#include <hip/hip_bf16.h>

typedef float    f32x4  __attribute__((ext_vector_type(4)));
typedef float    f32x16 __attribute__((ext_vector_type(16)));
typedef _Float16 f16x8  __attribute__((ext_vector_type(8)));
typedef _Float16 f16x4  __attribute__((ext_vector_type(4)));
typedef _Float16 f16x2  __attribute__((ext_vector_type(2)));

#define VP 258   // vlds co-pitch (stride 129 words === 1 mod 32: conflict-free)
#define XP 132   // xs plane-pitch (stride 66 words === 2 mod 32; 8B-aligned b64)

// ---------------------------------------------------------------------------
// Kernel 0: W [144][256] f32 -> wt [co(256)][tap(9)][kd(16)] fp16
// k' = tap*16 + kd ordering, matching the A-side fragment reads.
// ---------------------------------------------------------------------------
__global__ __launch_bounds__(256) void prep_wt_kernel(
    const float* __restrict__ W, _Float16* __restrict__ wt)
{
    const int k = blockIdx.x;      // 0..143 ; kd = k/9, tap = k%9
    const int t = threadIdx.x;     // co
    wt[t * 144 + (k % 9) * 16 + (k / 9)] = (_Float16)W[k * 256 + t];
}

// ---------------------------------------------------------------------------
// Fused kernel: block = (b,h). Conv (MFMA fp16, fp32 accum) writes votes
// straight to LDS; routing runs in-place. Votes never touch HBM.
// ---------------------------------------------------------------------------
__global__ __launch_bounds__(512, 2) void fused_kernel(
    const float* __restrict__ x, const _Float16* __restrict__ wt,
    const float* __restrict__ bias, float* __restrict__ out)
{
    const int h = blockIdx.x;   // 30
    const int b = blockIdx.y;   // 32
    const int t = threadIdx.x;  // 0..511

    __shared__ _Float16 vlds[8 * 30 * VP];          // 123,840 B
    __shared__ union {
        _Float16 xs[3][36][XP];                     // 28,512 B (conv phase)
        struct {                                    // routing phase
            _Float16 route16[8 * 16 * 30];          //  7,680 B
            _Float16 act16[30 * VP];                // 15,480 B
            float    s2buf[2][256];                 //  2,048 B
        } rt;
    } u;                                            // total 152,352 B

    // ---- stage x: rows h..h+2, 32 cols, 128 planes; fp16, plane-innermost
    {
        const float* xb = x + (size_t)b * 131072;
        for (int j = t; j < 3 * 4 * XP; j += 512) {      // zero cols 32..35
            int r = j / (4 * XP), rem = j - r * (4 * XP);
            int c = rem / XP, p = rem - c * XP;
            u.xs[r][32 + c][p] = (_Float16)0.f;
        }
        #pragma unroll
        for (int j = 0; j < 6; ++j) {
            int idx = t + j * 512;          // 0..3071 float4 granules
            int p   = idx / 24;             // plane
            int rem = idx - p * 24;
            int r   = rem >> 3;             // row 0..2
            int c4  = rem & 7;              // col quad
            f32x4 v = *(const f32x4*)(xb + p * 1024 + (h + r) * 32 + c4 * 4);
            u.xs[r][c4 * 4 + 0][p] = (_Float16)v[0];
            u.xs[r][c4 * 4 + 1][p] = (_Float16)v[1];
            u.xs[r][c4 * 4 + 2][p] = (_Float16)v[2];
            u.xs[r][c4 * 4 + 3][p] = (_Float16)v[3];
        }
    }
    __syncthreads();

    // ---- conv phase: wave wv owns co-tile wv; loop d; votes -> vlds
    {
        const int lane = t & 63, wv = t >> 6;
        const int l31 = lane & 31, kb = lane >> 5;
        const int co  = wv * 32 + l31;

        f16x8 bf[9];                        // B frags shared across all d
        const _Float16* wp = wt + (size_t)co * 144 + kb * 8;
        #pragma unroll
        for (int s = 0; s < 9; ++s) bf[s] = *(const f16x8*)(wp + s * 16);

        #pragma unroll 2
        for (int d = 0; d < 8; ++d) {
            f16x8 af[9];
            #pragma unroll
            for (int s = 0; s < 9; ++s) {
                const int kh = s / 3, kw = s - 3 * (s / 3);
                const _Float16* ap = &u.xs[kh][l31 + kw][d * 16 + kb * 8];
                f16x4 lo = *(const f16x4*)(ap);
                f16x4 hi = *(const f16x4*)(ap + 4);
                af[s] = __builtin_shufflevector(lo, hi, 0, 1, 2, 3, 4, 5, 6, 7);
            }
            f32x16 acc = {};
            #pragma unroll
            for (int s = 0; s < 9; ++s)
                acc = __builtin_amdgcn_mfma_f32_32x32x16_f16(af[s], bf[s], acc, 0, 0, 0);
            #pragma unroll
            for (int r = 0; r < 16; ++r) {
                const int w = (r & 3) + 8 * (r >> 2) + 4 * kb;
                if (w < 30) vlds[(d * 30 + w) * VP + co] = (_Float16)acc[r];
            }
        }
    }
    __syncthreads();

    // ---- routing phase (votes LDS-resident; logits in registers)
    const int oa = t & 255, wh = t >> 8;    // phase-B: (oa, w-half)
    const int o  = oa >> 4;
    const float bias_t = bias[oa];
    const int iA = t / 30, wA = t - iA * 30;  // phase-A/C mapping (t<240)

    float lreg[16];
    #pragma unroll
    for (int oo = 0; oo < 16; ++oo) lreg[oo] = 0.f;

    float pre[15];
    float scale = 0.f;

    for (int it = 0; it < 3; ++it) {
        // ---- Phase A: route = softmax_o(lreg); threads (i,w) t<240
        if (t < 240) {
            float m = lreg[0];
            #pragma unroll
            for (int oo = 1; oo < 16; ++oo) m = fmaxf(m, lreg[oo]);
            float e[16], ssum = 0.f;
            #pragma unroll
            for (int oo = 0; oo < 16; ++oo) { e[oo] = __expf(lreg[oo] - m); ssum += e[oo]; }
            float inv = 1.f / ssum;
            #pragma unroll
            for (int oo = 0; oo < 16; ++oo)
                u.rt.route16[(iA * 16 + oo) * 30 + wA] = (_Float16)(e[oo] * inv);
        }
        __syncthreads();

        // ---- Phase B: all 512 threads; thread (oa, wh) does w = wh*15..+14
        #pragma unroll
        for (int w = 0; w < 15; ++w) pre[w] = bias_t;
        #pragma unroll
        for (int i = 0; i < 8; ++i) {
            const _Float16* vrow = &vlds[(i * 30 + wh * 15) * VP + oa];
            const _Float16* rrow = &u.rt.route16[(i * 16 + o) * 30 + wh * 15];
            #pragma unroll
            for (int w = 0; w < 15; ++w)
                pre[w] = fmaf((float)rrow[w], (float)vrow[w * VP], pre[w]);
        }
        float s2p = 0.f;
        #pragma unroll
        for (int w = 0; w < 15; ++w) s2p = fmaf(pre[w], pre[w], s2p);
        u.rt.s2buf[wh][oa] = s2p;
        __syncthreads();
        float s2 = u.rt.s2buf[0][oa] + u.rt.s2buf[1][oa];
        scale = s2 / ((1.f + s2) * sqrtf(s2 + 1e-7f));

        if (it < 2) {
            #pragma unroll
            for (int w = 0; w < 15; ++w)
                u.rt.act16[(wh * 15 + w) * VP + oa] = (_Float16)(scale * pre[w]);
            __syncthreads();
            // ---- Phase C: thread (i,w) t<240: lreg[o] += sum_a v*act
            if (t < 240) {
                const _Float16* vrow = &vlds[(iA * 30 + wA) * VP];
                const _Float16* arow = &u.rt.act16[wA * VP];
                #pragma unroll
                for (int oo = 0; oo < 16; ++oo) {
                    float s = 0.f;
                    #pragma unroll
                    for (int k = 0; k < 8; ++k) {
                        f16x2 v2 = *(const f16x2*)&vrow[oo * 16 + 2 * k];
                        f16x2 a2 = *(const f16x2*)&arow[oo * 16 + 2 * k];
                        s = fmaf((float)v2[0], (float)a2[0], s);
                        s = fmaf((float)v2[1], (float)a2[1], s);
                    }
                    lreg[oo] += s;
                }
            }
            __syncthreads();
        }
    }

    // ---- output: out[b,h,w,o,a]; each thread stores its w-half, coalesced
    float* ob = out + (size_t)((b * 30 + h) * 30) * 256;
    #pragma unroll
    for (int w = 0; w < 15; ++w)
        ob[(wh * 15 + w) * 256 + oa] = scale * pre[w];
}

extern "C" void kernel_launch(void* const* d_in, const int* in_sizes, int n_in,
                              void* d_out, int out_size, void* d_ws, size_t ws_size,
                              hipStream_t stream)
{
    const float* x    = (const float*)d_in[0];  // [32,32,32,8,16] (raw-reshape view)
    const float* Wt   = (const float*)d_in[1];  // [16,3,3,1,256] = [144][256]
    const float* bias = (const float*)d_in[2];  // [16,16,1,1]
    float* out = (float*)d_out;                 // [32,30,30,16,16]
    _Float16* wt_h = (_Float16*)d_ws;           // [256][144] fp16 = 73,728 B

    prep_wt_kernel<<<dim3(144), 256, 0, stream>>>(Wt, wt_h);
    fused_kernel<<<dim3(30, 32), 512, 0, stream>>>(x, wt_h, bias, out);
}